// Round 2
// baseline (1202.974 us; speedup 1.0000x reference)
//
#include <hip/hip_runtime.h>
#include <hip/hip_cooperative_groups.h>
#include <math.h>

namespace cg = cooperative_groups;

#define NN    4096
#define CAP   128            // max list entries per node (deg ~42 incl self; huge margin)
#define GAMMA 0.99f
#define EPSF  1.1920929e-07f // np.finfo(np.float32).eps

// One cooperative kernel. Wave g (= blockIdx*4 + waveInBlock) owns node g.
// Phase 1: scan adj row g -> LDS neighbor list (self-loop seeded as entry 0),
//          lane-parallel r,s dot products. No sync needed (all wave-local).
// Phase 2: 10 value-iteration steps, one grid.sync() each, ping-pong A/B in ws.
//   k3v[i] = dinv_i * (sum_j A_j - s_i * sum_j B_j),  A_j = p_j*u_j, B_j = dinv_j*u_j
__global__ __launch_bounds__(256, 4) void gvin_fused(
    const float* __restrict__ adj,  const float* __restrict__ x,
    const float* __restrict__ comms,const float* __restrict__ mask,
    const float* __restrict__ Wr,   const float* __restrict__ br,
    const float* __restrict__ We,   const float* __restrict__ be,
    const float* __restrict__ w_emb,const float* __restrict__ b_emb,
    const float* __restrict__ Wa,   const float* __restrict__ ba,
    float* __restrict__ A0, float* __restrict__ B0,
    float* __restrict__ A1, float* __restrict__ B1,
    float* __restrict__ out)
{
    cg::grid_group grid = cg::this_grid();
    __shared__ int nbr[4][CAP];
    __shared__ int cnt_sh[4];
    const int wave = threadIdx.x >> 6;
    const int lane = threadIdx.x & 63;
    const int g = (int)blockIdx.x * 4 + wave;

    if (lane == 0) { cnt_sh[wave] = 1; nbr[wave][0] = g; }  // seed self (a_norm = adj + I)
    // LDS ops are program-ordered within a wave; no barrier needed for wave-local data.

    // ---- Phase 1a: adjacency row scan + compaction into LDS ----
    const float4* rowp = (const float4*)(adj + (size_t)g * NN);
#pragma unroll 4
    for (int it = 0; it < 16; ++it) {
        const int i4 = lane + it * 64;          // coalesced 16B/lane
        const float4 v = rowp[i4];
        const int base = i4 * 4;
        if (v.x != 0.0f) { int sl = atomicAdd(&cnt_sh[wave], 1); if (sl < CAP) nbr[wave][sl] = base;     }
        if (v.y != 0.0f) { int sl = atomicAdd(&cnt_sh[wave], 1); if (sl < CAP) nbr[wave][sl] = base + 1; }
        if (v.z != 0.0f) { int sl = atomicAdd(&cnt_sh[wave], 1); if (sl < CAP) nbr[wave][sl] = base + 2; }
        if (v.w != 0.0f) { int sl = atomicAdd(&cnt_sh[wave], 1); if (sl < CAP) nbr[wave][sl] = base + 3; }
    }

    // ---- Phase 1b: per-node scalars r = xc@Wr + br, s = (xc@We + be)@w_emb ----
    float pr = 0.0f, ps = 0.0f;
    if (lane < 32) {
        const float xc = (lane < 16) ? x[g * 16 + lane] : comms[g * 16 + (lane - 16)];
        float we = 0.0f;
#pragma unroll
        for (int c = 0; c < 8; ++c) we += We[lane * 8 + c] * w_emb[c];
        pr = xc * Wr[lane];
        ps = xc * we;
    } else if (lane == 32) {
#pragma unroll
        for (int c = 0; c < 8; ++c) ps += be[c] * w_emb[c];   // bias term of s
        pr = br[0];                                            // bias term of r
    }
#pragma unroll
    for (int off = 32; off; off >>= 1) {
        pr += __shfl_xor(pr, off);
        ps += __shfl_xor(ps, off);
    }
    const float r = pr, s = ps;   // all lanes hold the sums

    const int   deg  = cnt_sh[wave];                 // row sum of a_norm (incl self)
    const int   cl   = deg < CAP ? deg : CAP;        // stored list length
    const float dinv = sqrtf(1.0f / ((float)deg + EPSF));
    const float p    = dinv * (s + b_emb[0]);

    float wa[8], bb[8];
#pragma unroll
    for (int c = 0; c < 8; ++c) { wa[c] = Wa[c]; bb[c] = ba[c]; }

    // ---- Phase 2: 10 value-iteration steps, 1 grid sync each ----
    float u = r;      // u_0 = r + gamma*v0, v0 = 0
    float v = 0.0f;
    for (int t = 0; t < 10; ++t) {
        float* Aw = (t & 1) ? A1 : A0;   // ping-pong: write+read buf[t&1] this iter
        float* Bw = (t & 1) ? B1 : B0;
        if (lane == 0) { Aw[g] = p * u; Bw[g] = dinv * u; }
        grid.sync();                     // publishes all nodes' A/B for this step
        float S1 = 0.0f, S2 = 0.0f;
        for (int l = lane; l < cl; l += 64) {
            const int j = nbr[wave][l];
            S1 += Aw[j];
            S2 += Bw[j];
        }
#pragma unroll
        for (int off = 32; off; off >>= 1) {
            S1 += __shfl_xor(S1, off);
            S2 += __shfl_xor(S2, off);
        }
        const float k3v = dinv * (S1 - s * S2);
        v = fmaf(k3v, wa[0], bb[0]);
#pragma unroll
        for (int c = 1; c < 8; ++c) v = fmaxf(v, fmaf(k3v, wa[c], bb[c]));
        u = r + GAMMA * v;
    }

    if (lane == 0) out[g] = v + (mask[g] == 0.0f ? -INFINITY : 0.0f);
}

extern "C" void kernel_launch(void* const* d_in, const int* in_sizes, int n_in,
                              void* d_out, int out_size, void* d_ws, size_t ws_size,
                              hipStream_t stream) {
    const float* adj   = (const float*)d_in[2];
    const float* x     = (const float*)d_in[0];
    const float* comms = (const float*)d_in[1];
    const float* mask  = (const float*)d_in[3];
    const float* Wr    = (const float*)d_in[4];
    const float* br    = (const float*)d_in[5];
    const float* We    = (const float*)d_in[6];
    const float* be    = (const float*)d_in[7];
    const float* w_emb = (const float*)d_in[8];
    const float* b_emb = (const float*)d_in[9];
    const float* Wa    = (const float*)d_in[10];
    const float* ba    = (const float*)d_in[11];
    // d_in[12] = k (fixed at 10, hardcoded)

    char* ws = (char*)d_ws;
    float* A0 = (float*)(ws + 0 * NN * sizeof(float));
    float* B0 = (float*)(ws + 1 * NN * sizeof(float));
    float* A1 = (float*)(ws + 2 * NN * sizeof(float));
    float* B1 = (float*)(ws + 3 * NN * sizeof(float));
    float* out = (float*)d_out;

    void* args[] = {
        (void*)&adj, (void*)&x, (void*)&comms, (void*)&mask,
        (void*)&Wr, (void*)&br, (void*)&We, (void*)&be,
        (void*)&w_emb, (void*)&b_emb, (void*)&Wa, (void*)&ba,
        (void*)&A0, (void*)&B0, (void*)&A1, (void*)&B1, (void*)&out
    };
    hipLaunchCooperativeKernel((const void*)gvin_fused, dim3(NN / 4), dim3(256),
                               args, 0, stream);
}

// Round 3
// 225.780 us; speedup vs baseline: 5.3281x; 5.3281x over previous
//
#include <hip/hip_runtime.h>
#include <math.h>

#define NN      4096
#define CAP     128            // list slots per node (deg incl self ~42, max ~70)
#define PAD_IDX NN             // sentinel: AB[PAD_IDX] == (0,0)
#define GAMMA   0.99f
#define EPSF    1.1920929e-07f // np.finfo(np.float32).eps

// ---------------------------------------------------------------------------
// K1: fused adjacency compaction + per-node scalars. One wave per node.
//   nbr[g][0] = g (self, a_norm = adj + I), then nonzero cols, padded to x4
//   with PAD_IDX. meta[g] = (dinv, s, p, r).  AB0[g] = (p*r, dinv*r)  (u0 = r).
// ---------------------------------------------------------------------------
__global__ __launch_bounds__(256) void k_build(
    const float* __restrict__ adj, const float* __restrict__ x,
    const float* __restrict__ comms,
    const float* __restrict__ Wr, const float* __restrict__ br,
    const float* __restrict__ We, const float* __restrict__ be,
    const float* __restrict__ w_emb, const float* __restrict__ b_emb,
    int* __restrict__ nbr, int* __restrict__ cnt,
    float4* __restrict__ meta, float2* __restrict__ AB0, float2* __restrict__ AB1)
{
    __shared__ int lcnt[4];
    const int wave = threadIdx.x >> 6;
    const int lane = threadIdx.x & 63;
    const int g = blockIdx.x * 4 + wave;
    int* myrow = nbr + (size_t)g * CAP;
    if (lane == 0) { lcnt[wave] = 1; myrow[0] = g; }   // seed self-loop

    // stream the whole adj row into regs first (MLP: 16 independent 16B loads)
    const float4* rowp = (const float4*)(adj + (size_t)g * NN);
    float4 vv[16];
#pragma unroll
    for (int it = 0; it < 16; ++it) vv[it] = rowp[lane + it * 64];

    // per-node scalars while the row loads are in flight
    // r = xc@Wr + br ;  s = (xc@We + be)@w_emb  (We folded with w_emb per-row)
    float pr = 0.0f, ps = 0.0f;
    if (lane < 32) {
        const float xc = (lane < 16) ? x[g * 16 + lane] : comms[g * 16 + (lane - 16)];
        float we = 0.0f;
#pragma unroll
        for (int c = 0; c < 8; ++c) we += We[lane * 8 + c] * w_emb[c];
        pr = xc * Wr[lane];
        ps = xc * we;
    } else if (lane == 32) {
#pragma unroll
        for (int c = 0; c < 8; ++c) ps += be[c] * w_emb[c];
        pr = br[0];
    }
#pragma unroll
    for (int off = 32; off; off >>= 1) { pr += __shfl_xor(pr, off); ps += __shfl_xor(ps, off); }
    const float r = pr, s = ps;

    // compact nonzero columns (adj entries are exactly 0.0 or 1.0)
#pragma unroll
    for (int it = 0; it < 16; ++it) {
        const float4 v = vv[it];
        const int b4 = (lane + it * 64) * 4;
        if (v.x != 0.0f) { int sl = atomicAdd(&lcnt[wave], 1); if (sl < CAP) myrow[sl] = b4;     }
        if (v.y != 0.0f) { int sl = atomicAdd(&lcnt[wave], 1); if (sl < CAP) myrow[sl] = b4 + 1; }
        if (v.z != 0.0f) { int sl = atomicAdd(&lcnt[wave], 1); if (sl < CAP) myrow[sl] = b4 + 2; }
        if (v.w != 0.0f) { int sl = atomicAdd(&lcnt[wave], 1); if (sl < CAP) myrow[sl] = b4 + 3; }
    }
    const int deg = lcnt[wave];                       // row sum of a_norm incl self
    if (lane == 0) {
        const int cl = deg < CAP ? deg : CAP;
        cnt[g] = cl;
        for (int z = cl; z < ((cl + 3) & ~3); ++z) myrow[z] = PAD_IDX;  // pad to x4
        const float dinv = sqrtf(1.0f / ((float)deg + EPSF));
        const float p = dinv * (s + b_emb[0]);
        meta[g] = make_float4(dinv, s, p, r);
        AB0[g]  = make_float2(p * r, dinv * r);       // u0 = r (v0 = 0)
        if (g == 0) {
            AB0[PAD_IDX] = make_float2(0.0f, 0.0f);
            AB1[PAD_IDX] = make_float2(0.0f, 0.0f);   // ws is poison; sentinel must be 0
        }
    }
}

// ---------------------------------------------------------------------------
// K2: TWO value-iteration steps per launch via redundant 1-hop recompute.
// Wave owns node i; lane l owns j = nbr[i][l] and serially computes
//   S1_j,S2_j over N(j)u{j} from ABin  ->  v_j (step 2L+1) -> u_j -> A'_j,B'_j,
// then the wave reduces A',B' over j to get v_i (step 2L+2).
//   k3v = dinv*(S1 - s*S2);  v = max_c(k3v*Wa[c]+ba[c]);  u = r + g*v
// ---------------------------------------------------------------------------
__global__ __launch_bounds__(256) void k_step2(
    const int* __restrict__ nbr, const int* __restrict__ cnt,
    const float4* __restrict__ meta,
    const float2* __restrict__ ABin, float2* __restrict__ ABout,
    const float* __restrict__ Wa, const float* __restrict__ ba,
    const int is_final, const float* __restrict__ mask, float* __restrict__ out)
{
    const int i    = (blockIdx.x * 256 + threadIdx.x) >> 6;
    const int lane = threadIdx.x & 63;
    const int cl = cnt[i];
    float wa[8], bb[8];
#pragma unroll
    for (int c = 0; c < 8; ++c) { wa[c] = Wa[c]; bb[c] = ba[c]; }

    float TA = 0.0f, TB = 0.0f;
    for (int base = 0; base < cl; base += 64) {        // virtually always 1 chunk
        const int  l     = base + lane;
        const bool valid = l < cl;
        const int  j     = valid ? nbr[(size_t)i * CAP + l] : 0;
        float4 mj = make_float4(0.0f, 0.0f, 0.0f, 0.0f);
        int cj = 0;
        if (valid) { mj = meta[j]; cj = cnt[j]; }
        const int* nj = nbr + (size_t)j * CAP;
        const int cjp = (cj + 3) & ~3;                 // rows are padded with PAD_IDX
        float S1 = 0.0f, S2 = 0.0f;
        for (int k = 0; k < cjp; k += 4) {
            const int4 nn = *(const int4*)(nj + k);    // 16B-aligned (CAP*4 = 512B rows)
            const float2 a0 = ABin[nn.x];
            const float2 a1 = ABin[nn.y];
            const float2 a2 = ABin[nn.z];
            const float2 a3 = ABin[nn.w];
            S1 += (a0.x + a1.x) + (a2.x + a3.x);
            S2 += (a0.y + a1.y) + (a2.y + a3.y);
        }
        if (valid) {
            const float k3v = mj.x * (S1 - mj.y * S2); // step 2L+1 for node j
            float vj = fmaf(k3v, wa[0], bb[0]);
#pragma unroll
            for (int c = 1; c < 8; ++c) vj = fmaxf(vj, fmaf(k3v, wa[c], bb[c]));
            const float uj = mj.w + GAMMA * vj;
            TA += mj.z * uj;                           // A'_j = p_j * u_j
            TB += mj.x * uj;                           // B'_j = dinv_j * u_j
        }
    }
#pragma unroll
    for (int off = 32; off; off >>= 1) { TA += __shfl_xor(TA, off); TB += __shfl_xor(TB, off); }

    const float4 mi = meta[i];
    const float k3v = mi.x * (TA - mi.y * TB);         // step 2L+2 for node i
    float vi = fmaf(k3v, wa[0], bb[0]);
#pragma unroll
    for (int c = 1; c < 8; ++c) vi = fmaxf(vi, fmaf(k3v, wa[c], bb[c]));
    if (lane == 0) {
        if (is_final) {
            out[i] = vi + (mask[i] == 0.0f ? -INFINITY : 0.0f);
        } else {
            const float ui = mi.w + GAMMA * vi;
            ABout[i] = make_float2(mi.z * ui, mi.x * ui);
        }
    }
}

extern "C" void kernel_launch(void* const* d_in, const int* in_sizes, int n_in,
                              void* d_out, int out_size, void* d_ws, size_t ws_size,
                              hipStream_t stream) {
    const float* x     = (const float*)d_in[0];
    const float* comms = (const float*)d_in[1];
    const float* adj   = (const float*)d_in[2];
    const float* mask  = (const float*)d_in[3];
    const float* Wr    = (const float*)d_in[4];
    const float* br    = (const float*)d_in[5];
    const float* We    = (const float*)d_in[6];
    const float* be    = (const float*)d_in[7];
    const float* w_emb = (const float*)d_in[8];
    const float* b_emb = (const float*)d_in[9];
    const float* Wa    = (const float*)d_in[10];
    const float* ba    = (const float*)d_in[11];
    // d_in[12] = k, fixed at 10 -> 5 double-step launches

    char* ws = (char*)d_ws;
    size_t off = 0;
    int*    nbr  = (int*)(ws + off);    off += (size_t)NN * CAP * sizeof(int);   // 2 MB
    int*    cnt  = (int*)(ws + off);    off += (size_t)NN * sizeof(int);
    float4* meta = (float4*)(ws + off); off += (size_t)NN * sizeof(float4);
    float2* AB0  = (float2*)(ws + off); off += (size_t)(NN + 8) * sizeof(float2);
    float2* AB1  = (float2*)(ws + off); off += (size_t)(NN + 8) * sizeof(float2);
    float* out = (float*)d_out;

    k_build<<<NN / 4, 256, 0, stream>>>(adj, x, comms, Wr, br, We, be, w_emb, b_emb,
                                        nbr, cnt, meta, AB0, AB1);
    for (int L = 0; L < 5; ++L) {                      // each launch = 2 VI steps
        const float2* ABin  = (L & 1) ? AB1 : AB0;
        float2*       ABout = (L & 1) ? AB0 : AB1;
        const int is_final = (L == 4) ? 1 : 0;
        k_step2<<<NN / 4, 256, 0, stream>>>(nbr, cnt, meta, ABin, ABout,
                                            Wa, ba, is_final, mask, out);
    }
}

// Round 4
// 203.629 us; speedup vs baseline: 5.9077x; 1.1088x over previous
//
#include <hip/hip_runtime.h>
#include <math.h>

#define NN     4096
#define NB     256            // blocks (1 per CU, cooperative => co-resident)
#define TPB    1024           // 16 waves per block
#define WPB    16             // nodes (waves) per block
#define CAP    128            // neighbor slots per node (deg incl self ~42, max ~67)
#define GAMMA  0.99f
#define EPSF   1.1920929e-07f // np.finfo(np.float32).eps
#define MAGIC  1000           // generation base; ws poison 0xAAAAAAAA is negative as int
#define KSTEPS 10

union F2U { unsigned long long u; float2 f; };

// Lightweight LLC-scope grid barrier. All cross-block traffic is agent-scope
// relaxed atomics (sc1 -> served coherently by Infinity Cache, NO L2 flush).
// gen protocol: gen == MAGIC + (#barriers completed); block 0 inits ctr=0,
// gen=MAGIC at kernel start. Leaders gate their arrival on gen >= MAGIC+k-1,
// which (a) guarantees init happened before the first fetch_add and (b) is a
// no-op for later barriers. Last arriver resets ctr, then releases gen.
__device__ __forceinline__ void grid_barrier(int* ctr, int* gen, int k) {
    __syncthreads();   // compiler emits s_waitcnt vmcnt(0) before s_barrier:
                       // the whole block's agent stores are LLC-visible here.
    if (threadIdx.x == 0) {
        while (__hip_atomic_load(gen, __ATOMIC_RELAXED, __HIP_MEMORY_SCOPE_AGENT)
               < MAGIC + k - 1)
            __builtin_amdgcn_s_sleep(1);
        asm volatile("s_waitcnt vmcnt(0)" ::: "memory");
        const int old = __hip_atomic_fetch_add(ctr, 1, __ATOMIC_RELAXED,
                                               __HIP_MEMORY_SCOPE_AGENT);
        if (old == NB - 1) {
            __hip_atomic_store(ctr, 0, __ATOMIC_RELAXED, __HIP_MEMORY_SCOPE_AGENT);
            asm volatile("s_waitcnt vmcnt(0)" ::: "memory");  // ctr reset lands first
            __hip_atomic_store(gen, MAGIC + k, __ATOMIC_RELAXED,
                               __HIP_MEMORY_SCOPE_AGENT);
        } else {
            while (__hip_atomic_load(gen, __ATOMIC_RELAXED, __HIP_MEMORY_SCOPE_AGENT)
                   < MAGIC + k)
                __builtin_amdgcn_s_sleep(1);
        }
    }
    __syncthreads();
}

__global__ void __launch_bounds__(TPB, 4) gvin_persist(
    const float* __restrict__ adj,  const float* __restrict__ x,
    const float* __restrict__ comms,const float* __restrict__ mask,
    const float* __restrict__ Wr,   const float* __restrict__ br,
    const float* __restrict__ We,   const float* __restrict__ be,
    const float* __restrict__ w_emb,const float* __restrict__ b_emb,
    const float* __restrict__ Wa,   const float* __restrict__ ba,
    int* ctr, int* gen,
    unsigned long long* AB0, unsigned long long* AB1,
    float* __restrict__ out)
{
    __shared__ int nbr[WPB][CAP];
    __shared__ int lcnt[WPB];
    const int wave = threadIdx.x >> 6;
    const int lane = threadIdx.x & 63;
    const int g = (int)blockIdx.x * WPB + wave;

    if (blockIdx.x == 0 && threadIdx.x == 0) {       // init barrier state (ws is poison)
        __hip_atomic_store(ctr, 0, __ATOMIC_RELAXED, __HIP_MEMORY_SCOPE_AGENT);
        asm volatile("s_waitcnt vmcnt(0)" ::: "memory");
        __hip_atomic_store(gen, MAGIC, __ATOMIC_RELAXED, __HIP_MEMORY_SCOPE_AGENT);
    }

    if (lane == 0) { lcnt[wave] = 1; nbr[wave][0] = g; }   // self-loop (a_norm = adj+I)

    // ---- Phase 1: adj row scan -> LDS neighbor list (wave-local, no barrier) ----
    const float4* rowp = (const float4*)(adj + (size_t)g * NN);
#pragma unroll 4
    for (int it = 0; it < 16; ++it) {
        const float4 v = rowp[lane + it * 64];            // coalesced 16B/lane
        const int b4 = (lane + it * 64) * 4;
        if (v.x != 0.0f) { int sl = atomicAdd(&lcnt[wave], 1); if (sl < CAP) nbr[wave][sl] = b4;     }
        if (v.y != 0.0f) { int sl = atomicAdd(&lcnt[wave], 1); if (sl < CAP) nbr[wave][sl] = b4 + 1; }
        if (v.z != 0.0f) { int sl = atomicAdd(&lcnt[wave], 1); if (sl < CAP) nbr[wave][sl] = b4 + 2; }
        if (v.w != 0.0f) { int sl = atomicAdd(&lcnt[wave], 1); if (sl < CAP) nbr[wave][sl] = b4 + 3; }
    }

    // ---- per-node scalars: r = xc@Wr + br ; s = (xc@We + be)@w_emb ----
    float pr = 0.0f, ps = 0.0f;
    if (lane < 32) {
        const float xc = (lane < 16) ? x[g * 16 + lane] : comms[g * 16 + (lane - 16)];
        float we = 0.0f;
#pragma unroll
        for (int c = 0; c < 8; ++c) we += We[lane * 8 + c] * w_emb[c];
        pr = xc * Wr[lane];
        ps = xc * we;
    } else if (lane == 32) {
#pragma unroll
        for (int c = 0; c < 8; ++c) ps += be[c] * w_emb[c];
        pr = br[0];
    }
#pragma unroll
    for (int off = 32; off; off >>= 1) { pr += __shfl_xor(pr, off); ps += __shfl_xor(ps, off); }
    const float r = pr, s = ps;

    const int   deg  = lcnt[wave];
    const int   cl   = deg < CAP ? deg : CAP;
    const float dinv = sqrtf(1.0f / ((float)deg + EPSF));
    const float p    = dinv * (s + b_emb[0]);

    float wa[8], bb[8];
#pragma unroll
    for (int c = 0; c < 8; ++c) { wa[c] = Wa[c]; bb[c] = ba[c]; }

    if (lane == 0) {                                   // seed u0 = r (v0 = 0)
        F2U z; z.f = make_float2(p * r, dinv * r);
        __hip_atomic_store(AB0 + g, z.u, __ATOMIC_RELAXED, __HIP_MEMORY_SCOPE_AGENT);
    }

    // ---- Phase 2: 10 VI steps, one LLC barrier each, ping-pong AB buffers ----
    float v = 0.0f;
    for (int t = 0; t < KSTEPS; ++t) {
        grid_barrier(ctr, gen, t + 1);                 // publishes step-t inputs
        const unsigned long long* ABin  = (t & 1) ? AB1 : AB0;
        unsigned long long*       ABout = (t & 1) ? AB0 : AB1;
        float S1 = 0.0f, S2 = 0.0f;
        for (int l = lane; l < cl; l += 64) {          // <=2 iterations (deg max ~67)
            const int j = nbr[wave][l];
            F2U z;
            z.u = __hip_atomic_load(ABin + j, __ATOMIC_RELAXED, __HIP_MEMORY_SCOPE_AGENT);
            S1 += z.f.x;
            S2 += z.f.y;
        }
#pragma unroll
        for (int off = 32; off; off >>= 1) { S1 += __shfl_xor(S1, off); S2 += __shfl_xor(S2, off); }
        const float k3v = dinv * (S1 - s * S2);
        v = fmaf(k3v, wa[0], bb[0]);
#pragma unroll
        for (int c = 1; c < 8; ++c) v = fmaxf(v, fmaf(k3v, wa[c], bb[c]));
        if (t < KSTEPS - 1 && lane == 0) {
            const float u = r + GAMMA * v;
            F2U z; z.f = make_float2(p * u, dinv * u);
            __hip_atomic_store(ABout + g, z.u, __ATOMIC_RELAXED, __HIP_MEMORY_SCOPE_AGENT);
        }
    }

    if (lane == 0) out[g] = v + (mask[g] == 0.0f ? -INFINITY : 0.0f);
}

extern "C" void kernel_launch(void* const* d_in, const int* in_sizes, int n_in,
                              void* d_out, int out_size, void* d_ws, size_t ws_size,
                              hipStream_t stream) {
    const float* x     = (const float*)d_in[0];
    const float* comms = (const float*)d_in[1];
    const float* adj   = (const float*)d_in[2];
    const float* mask  = (const float*)d_in[3];
    const float* Wr    = (const float*)d_in[4];
    const float* br    = (const float*)d_in[5];
    const float* We    = (const float*)d_in[6];
    const float* be    = (const float*)d_in[7];
    const float* w_emb = (const float*)d_in[8];
    const float* b_emb = (const float*)d_in[9];
    const float* Wa    = (const float*)d_in[10];
    const float* ba    = (const float*)d_in[11];
    // d_in[12] = k (fixed at 10, hardcoded)

    char* ws = (char*)d_ws;
    int* ctr = (int*)(ws + 0);                        // own cacheline
    int* gen = (int*)(ws + 256);                      // own cacheline
    unsigned long long* AB0 = (unsigned long long*)(ws + 1024);
    unsigned long long* AB1 = (unsigned long long*)(ws + 1024 + (size_t)NN * 8);
    float* out = (float*)d_out;

    void* args[] = {
        (void*)&adj, (void*)&x, (void*)&comms, (void*)&mask,
        (void*)&Wr, (void*)&br, (void*)&We, (void*)&be,
        (void*)&w_emb, (void*)&b_emb, (void*)&Wa, (void*)&ba,
        (void*)&ctr, (void*)&gen, (void*)&AB0, (void*)&AB1, (void*)&out
    };
    hipLaunchCooperativeKernel((const void*)gvin_persist, dim3(NB), dim3(TPB),
                               args, 0, stream);
}

// Round 5
// 180.497 us; speedup vs baseline: 6.6648x; 1.1282x over previous
//
#include <hip/hip_runtime.h>
#include <math.h>

#define NN     4096
#define NB     256            // blocks; co-residency by capacity (see launch comment)
#define TPB    1024           // 16 waves per block
#define WPB    16             // nodes (waves) per block
#define CAP    128            // neighbor slots per node (deg incl self ~42, max ~67)
#define GAMMA  0.99f
#define EPSF   1.1920929e-07f // np.finfo(np.float32).eps
#define MAGIC  1000           // generation base; ws poison 0xAAAAAAAA is negative as int
#define KSTEPS 10

union F2U { unsigned long long u; float2 f; };

// LLC-scope grid barrier (validated round 4: absmax 0.0). All cross-block
// traffic is agent-scope relaxed atomics (served coherently by the Infinity
// Cache; no L2 flush). gen == MAGIC + (#barriers completed). Block 0 inits
// ctr=0, gen=MAGIC; leaders gate arrival k on gen >= MAGIC+k-1 (covers init
// race and is a no-op later). Last arriver resets ctr then releases gen.
// __syncthreads makes EACH wave drain its own vmcnt before s_barrier (measured
// compiler behavior), so all block stores are LLC-visible before the leader
// arrives.
__device__ __forceinline__ void grid_barrier(int* ctr, int* gen, int k) {
    __syncthreads();
    if (threadIdx.x == 0) {
        while (__hip_atomic_load(gen, __ATOMIC_RELAXED, __HIP_MEMORY_SCOPE_AGENT)
               < MAGIC + k - 1)
            __builtin_amdgcn_s_sleep(1);
        asm volatile("s_waitcnt vmcnt(0)" ::: "memory");
        const int old = __hip_atomic_fetch_add(ctr, 1, __ATOMIC_RELAXED,
                                               __HIP_MEMORY_SCOPE_AGENT);
        if (old == NB - 1) {
            __hip_atomic_store(ctr, 0, __ATOMIC_RELAXED, __HIP_MEMORY_SCOPE_AGENT);
            asm volatile("s_waitcnt vmcnt(0)" ::: "memory");  // ctr reset lands first
            __hip_atomic_store(gen, MAGIC + k, __ATOMIC_RELAXED,
                               __HIP_MEMORY_SCOPE_AGENT);
        } else {
            while (__hip_atomic_load(gen, __ATOMIC_RELAXED, __HIP_MEMORY_SCOPE_AGENT)
                   < MAGIC + k)
                __builtin_amdgcn_s_sleep(1);
        }
    }
    __syncthreads();
}

__global__ void __launch_bounds__(TPB) gvin_persist(
    const float* __restrict__ adj,  const float* __restrict__ x,
    const float* __restrict__ comms,const float* __restrict__ mask,
    const float* __restrict__ Wr,   const float* __restrict__ br,
    const float* __restrict__ We,   const float* __restrict__ be,
    const float* __restrict__ w_emb,const float* __restrict__ b_emb,
    const float* __restrict__ Wa,   const float* __restrict__ ba,
    int* ctr, int* gen,
    unsigned long long* AB0, unsigned long long* AB1,
    float* __restrict__ out)
{
    __shared__ unsigned long long ab_lds[NN];   // 32 KB: full AB table per step
    __shared__ int nbr[WPB][CAP];               // 8 KB
    __shared__ int lcnt[WPB];
    const int wave = threadIdx.x >> 6;
    const int lane = threadIdx.x & 63;
    const int g = (int)blockIdx.x * WPB + wave;

    if (blockIdx.x == 0 && threadIdx.x == 0) {  // init barrier state (ws is poison)
        __hip_atomic_store(ctr, 0, __ATOMIC_RELAXED, __HIP_MEMORY_SCOPE_AGENT);
        asm volatile("s_waitcnt vmcnt(0)" ::: "memory");
        __hip_atomic_store(gen, MAGIC, __ATOMIC_RELAXED, __HIP_MEMORY_SCOPE_AGENT);
    }

    if (lane == 0) { lcnt[wave] = 1; nbr[wave][0] = g; }   // self-loop (a_norm = adj+I)

    // ---- Phase 1: adj row scan -> LDS neighbor list (wave-local, no barrier) ----
    const float4* rowp = (const float4*)(adj + (size_t)g * NN);
#pragma unroll 4
    for (int it = 0; it < 16; ++it) {
        const float4 v = rowp[lane + it * 64];            // coalesced 16B/lane
        const int b4 = (lane + it * 64) * 4;
        if (v.x != 0.0f) { int sl = atomicAdd(&lcnt[wave], 1); if (sl < CAP) nbr[wave][sl] = b4;     }
        if (v.y != 0.0f) { int sl = atomicAdd(&lcnt[wave], 1); if (sl < CAP) nbr[wave][sl] = b4 + 1; }
        if (v.z != 0.0f) { int sl = atomicAdd(&lcnt[wave], 1); if (sl < CAP) nbr[wave][sl] = b4 + 2; }
        if (v.w != 0.0f) { int sl = atomicAdd(&lcnt[wave], 1); if (sl < CAP) nbr[wave][sl] = b4 + 3; }
    }

    // ---- per-node scalars: r = xc@Wr + br ; s = (xc@We + be)@w_emb ----
    float pr = 0.0f, ps = 0.0f;
    if (lane < 32) {
        const float xc = (lane < 16) ? x[g * 16 + lane] : comms[g * 16 + (lane - 16)];
        float we = 0.0f;
#pragma unroll
        for (int c = 0; c < 8; ++c) we += We[lane * 8 + c] * w_emb[c];
        pr = xc * Wr[lane];
        ps = xc * we;
    } else if (lane == 32) {
#pragma unroll
        for (int c = 0; c < 8; ++c) ps += be[c] * w_emb[c];
        pr = br[0];
    }
#pragma unroll
    for (int off = 32; off; off >>= 1) { pr += __shfl_xor(pr, off); ps += __shfl_xor(ps, off); }
    const float r = pr, s = ps;

    const int   deg  = lcnt[wave];
    const int   cl   = deg < CAP ? deg : CAP;
    const float dinv = sqrtf(1.0f / ((float)deg + EPSF));
    const float p    = dinv * (s + b_emb[0]);

    float wa[8], bb[8];
#pragma unroll
    for (int c = 0; c < 8; ++c) { wa[c] = Wa[c]; bb[c] = ba[c]; }

    if (lane == 0) {                                   // seed u0 = r (v0 = 0)
        F2U z; z.f = make_float2(p * r, dinv * r);
        __hip_atomic_store(AB0 + g, z.u, __ATOMIC_RELAXED, __HIP_MEMORY_SCOPE_AGENT);
    }

    // ---- Phase 2: 10 VI steps. Per step: barrier -> coalesced agent-scope
    // broadcast of the 32 KB AB table into LDS -> LDS gather -> store AB'. ----
    float v = 0.0f;
    for (int t = 0; t < KSTEPS; ++t) {
        grid_barrier(ctr, gen, t + 1);                 // publishes step-t inputs
        const unsigned long long* ABin  = (t & 1) ? AB1 : AB0;
        unsigned long long*       ABout = (t & 1) ? AB0 : AB1;
#pragma unroll
        for (int it = 0; it < NN / TPB; ++it) {        // 4 coalesced 8B/lane passes
            const int idx = threadIdx.x + it * TPB;
            ab_lds[idx] = __hip_atomic_load(ABin + idx, __ATOMIC_RELAXED,
                                            __HIP_MEMORY_SCOPE_AGENT);
        }
        __syncthreads();                               // ab_lds ready
        float S1 = 0.0f, S2 = 0.0f;
        for (int l = lane; l < cl; l += 64) {          // <=2 iterations (deg max ~67)
            F2U z; z.u = ab_lds[nbr[wave][l]];
            S1 += z.f.x;
            S2 += z.f.y;
        }
#pragma unroll
        for (int off = 32; off; off >>= 1) { S1 += __shfl_xor(S1, off); S2 += __shfl_xor(S2, off); }
        const float k3v = dinv * (S1 - s * S2);
        v = fmaf(k3v, wa[0], bb[0]);
#pragma unroll
        for (int c = 1; c < 8; ++c) v = fmaxf(v, fmaf(k3v, wa[c], bb[c]));
        if (t < KSTEPS - 1 && lane == 0) {
            const float u = r + GAMMA * v;
            F2U z; z.f = make_float2(p * u, dinv * u);
            __hip_atomic_store(ABout + g, z.u, __ATOMIC_RELAXED, __HIP_MEMORY_SCOPE_AGENT);
        }
        // next grid_barrier's __syncthreads separates this step's ab_lds reads
        // from the next step's overwrites (no extra block sync needed)
    }

    if (lane == 0) out[g] = v + (mask[g] == 0.0f ? -INFINITY : 0.0f);
}

extern "C" void kernel_launch(void* const* d_in, const int* in_sizes, int n_in,
                              void* d_out, int out_size, void* d_ws, size_t ws_size,
                              hipStream_t stream) {
    const float* x     = (const float*)d_in[0];
    const float* comms = (const float*)d_in[1];
    const float* adj   = (const float*)d_in[2];
    const float* mask  = (const float*)d_in[3];
    const float* Wr    = (const float*)d_in[4];
    const float* br    = (const float*)d_in[5];
    const float* We    = (const float*)d_in[6];
    const float* be    = (const float*)d_in[7];
    const float* w_emb = (const float*)d_in[8];
    const float* b_emb = (const float*)d_in[9];
    const float* Wa    = (const float*)d_in[10];
    const float* ba    = (const float*)d_in[11];
    // d_in[12] = k (fixed at 10, hardcoded)

    char* ws = (char*)d_ws;
    int* ctr = (int*)(ws + 0);                        // own cacheline
    int* gen = (int*)(ws + 256);                      // own cacheline
    unsigned long long* AB0 = (unsigned long long*)(ws + 1024);
    unsigned long long* AB1 = (unsigned long long*)(ws + 1024 + (size_t)NN * 8);
    float* out = (float*)d_out;

    // PLAIN launch (not cooperative): co-residency is guaranteed by capacity.
    // Each block: 16 waves (of 32/CU), 16 VGPR, ~41 KB LDS (of 160 KB) -> every
    // CU accepts >=2 blocks, so 256 blocks <= 256 CUs are all resident before
    // any barrier wait regardless of packing. Cooperative launch measured
    // ~128 us of launch overhead (round 4: bench 204 us vs kernel 76 us).
    gvin_persist<<<dim3(NB), dim3(TPB), 0, stream>>>(
        adj, x, comms, mask, Wr, br, We, be, w_emb, b_emb, Wa, ba,
        ctr, gen, AB0, AB1, out);
}

// Round 6
// 156.012 us; speedup vs baseline: 7.7108x; 1.1569x over previous
//
#include <hip/hip_runtime.h>
#include <math.h>

#define NN     4096
#define NB     256            // blocks; co-residency by capacity (see launch comment)
#define TPB    1024           // 16 waves per block
#define WPB    16             // nodes (waves) per block
#define CAP    128            // neighbor slots per node (deg incl self ~42, max ~67)
#define GAMMA  0.99f
#define EPSF   1.1920929e-07f // np.finfo(np.float32).eps
#define KSTEPS 10

union F2U { unsigned long long u; float2 f; };

// Contention-free LLC-scope grid barrier.
//   arrival: block b STORES arr[b] = k  (256 parallel stores, distinct addrs —
//            no RMW serialization; round 5 showed the contended single-counter
//            fetch_add chain cost ~5 us/step)
//   detect : block 0 wave 0 polls all 256 flags (4 per lane, int loads) until
//            __all(arr[i] >= k), then lane 0 stores gen = k
//   release: other block leaders spin on gen >= k
// Poison-safe with NO init: ws poison 0xAAAAAAAA is negative as signed int, so
// ">= k" (k >= 1) is false until genuinely written; flags are monotonic so no
// reset is ever needed. All cross-block traffic is agent-scope relaxed atomics
// (coherent at the Infinity Cache; no L2 flush). Visibility: each wave's AB
// stores are vmcnt-acked at __syncthreads (measured compiler behavior), so the
// leader's arrival store is LLC-ordered after them; master reads flag -> stores
// gen; spinner reads gen -> its gathers hit committed LLC data.
__device__ __forceinline__ void grid_barrier(int* arr, int* gen, int k) {
    __syncthreads();
    if (threadIdx.x == 0)
        __hip_atomic_store(arr + blockIdx.x, k, __ATOMIC_RELAXED,
                           __HIP_MEMORY_SCOPE_AGENT);
    if (blockIdx.x == 0) {
        if (threadIdx.x < 64) {                       // wave 0 polls 256 flags
            const int base = threadIdx.x * 4;
            for (;;) {
                const int a0 = __hip_atomic_load(arr + base + 0, __ATOMIC_RELAXED, __HIP_MEMORY_SCOPE_AGENT);
                const int a1 = __hip_atomic_load(arr + base + 1, __ATOMIC_RELAXED, __HIP_MEMORY_SCOPE_AGENT);
                const int a2 = __hip_atomic_load(arr + base + 2, __ATOMIC_RELAXED, __HIP_MEMORY_SCOPE_AGENT);
                const int a3 = __hip_atomic_load(arr + base + 3, __ATOMIC_RELAXED, __HIP_MEMORY_SCOPE_AGENT);
                if (__all((a0 >= k) && (a1 >= k) && (a2 >= k) && (a3 >= k))) break;
                __builtin_amdgcn_s_sleep(1);
            }
            if (threadIdx.x == 0) {
                asm volatile("s_waitcnt vmcnt(0)" ::: "memory");
                __hip_atomic_store(gen, k, __ATOMIC_RELAXED, __HIP_MEMORY_SCOPE_AGENT);
            }
        }
    } else if (threadIdx.x == 0) {
        while (__hip_atomic_load(gen, __ATOMIC_RELAXED, __HIP_MEMORY_SCOPE_AGENT) < k)
            __builtin_amdgcn_s_sleep(1);
    }
    __syncthreads();
}

__global__ void __launch_bounds__(TPB) gvin_persist(
    const float* __restrict__ adj,  const float* __restrict__ x,
    const float* __restrict__ comms,const float* __restrict__ mask,
    const float* __restrict__ Wr,   const float* __restrict__ br,
    const float* __restrict__ We,   const float* __restrict__ be,
    const float* __restrict__ w_emb,const float* __restrict__ b_emb,
    const float* __restrict__ Wa,   const float* __restrict__ ba,
    int* arr, int* gen,
    unsigned long long* AB0, unsigned long long* AB1,
    float* __restrict__ out)
{
    __shared__ int nbr[WPB][CAP];               // 8 KB
    __shared__ int lcnt[WPB];
    const int wave = threadIdx.x >> 6;
    const int lane = threadIdx.x & 63;
    const int g = (int)blockIdx.x * WPB + wave;

    if (lane == 0) { lcnt[wave] = 1; nbr[wave][0] = g; }   // self-loop (a_norm = adj+I)

    // ---- Phase 1: adj row scan -> LDS neighbor list (wave-local, no barrier) ----
    const float4* rowp = (const float4*)(adj + (size_t)g * NN);
#pragma unroll 4
    for (int it = 0; it < 16; ++it) {
        const float4 v = rowp[lane + it * 64];            // coalesced 16B/lane
        const int b4 = (lane + it * 64) * 4;
        if (v.x != 0.0f) { int sl = atomicAdd(&lcnt[wave], 1); if (sl < CAP) nbr[wave][sl] = b4;     }
        if (v.y != 0.0f) { int sl = atomicAdd(&lcnt[wave], 1); if (sl < CAP) nbr[wave][sl] = b4 + 1; }
        if (v.z != 0.0f) { int sl = atomicAdd(&lcnt[wave], 1); if (sl < CAP) nbr[wave][sl] = b4 + 2; }
        if (v.w != 0.0f) { int sl = atomicAdd(&lcnt[wave], 1); if (sl < CAP) nbr[wave][sl] = b4 + 3; }
    }

    // ---- per-node scalars: r = xc@Wr + br ; s = (xc@We + be)@w_emb ----
    float pr = 0.0f, ps = 0.0f;
    if (lane < 32) {
        const float xc = (lane < 16) ? x[g * 16 + lane] : comms[g * 16 + (lane - 16)];
        float we = 0.0f;
#pragma unroll
        for (int c = 0; c < 8; ++c) we += We[lane * 8 + c] * w_emb[c];
        pr = xc * Wr[lane];
        ps = xc * we;
    } else if (lane == 32) {
#pragma unroll
        for (int c = 0; c < 8; ++c) ps += be[c] * w_emb[c];
        pr = br[0];
    }
#pragma unroll
    for (int off = 32; off; off >>= 1) { pr += __shfl_xor(pr, off); ps += __shfl_xor(ps, off); }
    const float r = pr, s = ps;

    const int   deg  = lcnt[wave];
    const int   cl   = deg < CAP ? deg : CAP;
    const float dinv = sqrtf(1.0f / ((float)deg + EPSF));
    const float p    = dinv * (s + b_emb[0]);

    // hoist neighbor indices to registers: steps touch no LDS at all
    const bool val0 = lane < cl;
    const bool val1 = 64 + lane < cl;                 // deg max ~67 => <=2 chunks
    const int  j0   = val0 ? nbr[wave][lane] : g;
    const int  j1   = val1 ? nbr[wave][64 + lane] : g;

    float wa[8], bb[8];
#pragma unroll
    for (int c = 0; c < 8; ++c) { wa[c] = Wa[c]; bb[c] = ba[c]; }

    if (lane == 0) {                                   // seed u0 = r (v0 = 0)
        F2U z; z.f = make_float2(p * r, dinv * r);
        __hip_atomic_store(AB0 + g, z.u, __ATOMIC_RELAXED, __HIP_MEMORY_SCOPE_AGENT);
    }

    // ---- Phase 2: 10 VI steps; flag barrier + direct LLC gathers (round-4 style) ----
    float v = 0.0f;
    for (int t = 0; t < KSTEPS; ++t) {
        grid_barrier(arr, gen, t + 1);                 // publishes step-t inputs
        const unsigned long long* ABin  = (t & 1) ? AB1 : AB0;
        unsigned long long*       ABout = (t & 1) ? AB0 : AB1;
        F2U z0, z1;
        z0.u = __hip_atomic_load(ABin + j0, __ATOMIC_RELAXED, __HIP_MEMORY_SCOPE_AGENT);
        z1.u = __hip_atomic_load(ABin + j1, __ATOMIC_RELAXED, __HIP_MEMORY_SCOPE_AGENT);
        float S1 = val0 ? z0.f.x : 0.0f;
        float S2 = val0 ? z0.f.y : 0.0f;
        if (val1) { S1 += z1.f.x; S2 += z1.f.y; }
#pragma unroll
        for (int off = 32; off; off >>= 1) { S1 += __shfl_xor(S1, off); S2 += __shfl_xor(S2, off); }
        const float k3v = dinv * (S1 - s * S2);
        v = fmaf(k3v, wa[0], bb[0]);
#pragma unroll
        for (int c = 1; c < 8; ++c) v = fmaxf(v, fmaf(k3v, wa[c], bb[c]));
        if (t < KSTEPS - 1 && lane == 0) {
            const float u = r + GAMMA * v;
            F2U z; z.f = make_float2(p * u, dinv * u);
            __hip_atomic_store(ABout + g, z.u, __ATOMIC_RELAXED, __HIP_MEMORY_SCOPE_AGENT);
        }
    }

    if (lane == 0) out[g] = v + (mask[g] == 0.0f ? -INFINITY : 0.0f);
}

extern "C" void kernel_launch(void* const* d_in, const int* in_sizes, int n_in,
                              void* d_out, int out_size, void* d_ws, size_t ws_size,
                              hipStream_t stream) {
    const float* x     = (const float*)d_in[0];
    const float* comms = (const float*)d_in[1];
    const float* adj   = (const float*)d_in[2];
    const float* mask  = (const float*)d_in[3];
    const float* Wr    = (const float*)d_in[4];
    const float* br    = (const float*)d_in[5];
    const float* We    = (const float*)d_in[6];
    const float* be    = (const float*)d_in[7];
    const float* w_emb = (const float*)d_in[8];
    const float* b_emb = (const float*)d_in[9];
    const float* Wa    = (const float*)d_in[10];
    const float* ba    = (const float*)d_in[11];
    // d_in[12] = k (fixed at 10, hardcoded)

    char* ws = (char*)d_ws;
    int* arr = (int*)(ws + 0);                        // 256 flags (4 cache lines)
    int* gen = (int*)(ws + 4096);                     // own line
    unsigned long long* AB0 = (unsigned long long*)(ws + 8192);
    unsigned long long* AB1 = (unsigned long long*)(ws + 8192 + (size_t)NN * 8);
    float* out = (float*)d_out;

    // PLAIN launch: co-residency by capacity (16 waves of 32/CU, 20 VGPR,
    // ~8.5 KB LDS -> every CU accepts 2 blocks; all 256 blocks resident
    // immediately). Cooperative launch measured +28 us overhead (r4 vs r5).
    gvin_persist<<<dim3(NB), dim3(TPB), 0, stream>>>(
        adj, x, comms, mask, Wr, br, We, be, w_emb, b_emb, Wa, ba,
        arr, gen, AB0, AB1, out);
}